// Round 6
// baseline (586.062 us; speedup 1.0000x reference)
//
#include <hip/hip_runtime.h>
#include <hip/hip_fp16.h>
#include <math.h>

typedef unsigned int uint;
typedef unsigned short ushort;
typedef short f16x8 __attribute__((ext_vector_type(8)));
typedef float f32x4 __attribute__((ext_vector_type(4)));

#define NLPOW 1.4f
#define EPSF 1e-8f
#define HO 129

__device__ __forceinline__ float activate(float c) {
    c = fmaxf(c, 0.0f);
    return powf(c, NLPOW);
}

// f16 split with scaled residual: v ~= h + l/2048 (h,l = f16 bit patterns)
__device__ __forceinline__ void f16split(float v, ushort& h, ushort& l) {
    __half hv = __float2half(v);           // RNE
    h = __half_as_ushort(hv);
    float r = (v - __half2float(hv)) * 2048.0f;
    l = __half_as_ushort(__float2half(r));
}

__device__ __forceinline__ void gld_lds16(const ushort* g, ushort* l) {
    __builtin_amdgcn_global_load_lds(
        (const __attribute__((address_space(1))) void*)g,
        (__attribute__((address_space(3))) void*)l,
        16, 0, 0);
}

// ---------------- prep: padded channel-last f16-split of desc2 ----------------
// d2p[yp:140][xp:148][plane:2][c:128] ushort; plane0 = h, plane1 = l (scaled residual)
__global__ void prep_d2(const float* __restrict__ d2, ushort* __restrict__ d2p) {
    int idx = blockIdx.x * 256 + threadIdx.x;
    if (idx >= 140 * 148 * 128) return;
    int c = idx & 127;
    int xp = (idx >> 7) % 148;
    int yp = idx / (148 * 128);
    int y = yp - 2, x = xp - 2;
    float v = 0.f;
    if ((unsigned)y < 128u && (unsigned)x < 128u)
        v = d2[c * 16384 + y * 128 + x];
    ushort h, lo;
    f16split(v, h, lo);
    long o = ((long)(yp * 148 + xp)) * 256 + c;
    d2p[o] = h;
    d2p[o + 128] = lo;
}

// ---------------- prep: A in linear LDS-image layout, stride 40 ----------------
// Ag[mb][s][plane:2][128 rows][40 kk] ushort (kk<32 valid); k' = s*32+kk = (a*4+b)*128 + c
__global__ void build_Afrag(const float* __restrict__ d1, ushort* __restrict__ Ag) {
    int idx = blockIdx.x * 256 + threadIdx.x;
    if (idx >= 8 * 64 * 2 * 128 * 40) return;
    int kk = idx % 40;
    int row = (idx / 40) % 128;
    int pl = (idx / 5120) % 2;
    int s = (idx / 10240) % 64;
    int mb = idx / 655360;
    ushort hv = 0, lv = 0;
    if (kk < 32) {
        int kp = s * 32 + kk;
        int c = kp & 127;
        int ab = kp >> 7;
        int a = ab >> 2, b = ab & 3;
        int p = mb * 128 + row;
        int i = p >> 5, j = p & 31;
        float v = d1[c * 16384 + (4 * i + a) * 128 + (4 * j + b)];
        f16split(v, hv, lv);
    }
    Ag[idx] = pl ? lv : hv;
}

// ---------------- pnorm[p] from d1 directly ----------------
__global__ void pnorm_k(const float* __restrict__ d1, float* __restrict__ pn) {
    int p = blockIdx.x;
    int t = threadIdx.x;
    int i = p >> 5, j = p & 31;
    int pix = t & 15;
    int a = pix >> 2, b = pix & 3;
    int cg = t >> 4;
    const float* base = d1 + (4 * i + a) * 128 + (4 * j + b);
    float s = 0.f;
    for (int c = cg * 32; c < cg * 32 + 32; ++c) {
        float v = base[c * 16384];
        s += v * v;
    }
    #pragma unroll
    for (int off = 32; off > 0; off >>= 1) s += __shfl_down(s, off);
    if (t == 0) pn[p] = sqrtf(s);
}

// ---------------- sq[y][x] = sum_c desc2^2 ----------------
__global__ void sq_k(const float* __restrict__ d2, float* __restrict__ sq) {
    int idx = blockIdx.x * 256 + threadIdx.x;
    if (idx >= 16384) return;
    float s = 0.f;
    for (int c = 0; c < 128; ++c) {
        float v = d2[c * 16384 + idx];
        s += v * v;
    }
    sq[idx] = s;
}

// ---------------- wnorm ----------------
__global__ void wnorm_k(const float* __restrict__ sq, float* __restrict__ wnorm) {
    int idx = blockIdx.x * 256 + threadIdx.x;
    if (idx >= HO * HO) return;
    int y = idx / HO, x = idx % HO;
    float s = 0.f;
    #pragma unroll
    for (int a = 0; a < 4; ++a) {
        int yy = y - 2 + a;
        if ((unsigned)yy >= 128u) continue;
        #pragma unroll
        for (int b = 0; b < 4; ++b) {
            int xx = x - 2 + b;
            if ((unsigned)xx >= 128u) continue;
            s += sq[yy * 128 + xx];
        }
    }
    wnorm[idx] = sqrtf(s);
}

// ---------------- main correlation: f16-split 3-stream MFMA implicit GEMM ----------------
// M=1024, N=129x129 (tiled 8y x 16x), K=2048 over 64 steps of 32.
// corr = accH + accX/2048. XCD-pinned mb. LDS 81920 B -> 2 blocks/CU.
// One barrier per step (double-buffered; stageA/writeB target buf^1 only).
__global__ __launch_bounds__(256, 2) void conv_mfma(
    const ushort* __restrict__ Ag,     // [mb][s][2][128][40]
    const ushort* __restrict__ d2p,    // [140][148][2][128] f16 channel-last h/l
    const float* __restrict__ pn, const float* __restrict__ wnorm,
    float* __restrict__ out)
{
    __shared__ __align__(16) ushort A2[2][2][5120];   // [buf][plane][row*40]
    __shared__ __align__(16) ushort B2[2][2][5120];

    const int t = threadIdx.x;
    const int mb = blockIdx.x & 7;        // XCD-pinned M-panel
    const int nb = blockIdx.x >> 3;       // 0..152
    const int ny0 = (nb / 9) * 8;
    const int nx0 = (nb % 9) * 16;
    const int p0 = mb * 128;

    const int l = t & 63;
    const int w = t >> 6;
    const int wm = w & 1, wn_ = w >> 1;
    const int lm = l & 15, lg = l >> 4;

    // B staging mapping: row n = t>>1 (y=n>>4, x=n&15), half = t&1 (16 channels)
    const int bn = t >> 1;
    const int bh = t & 1;
    const int bdy = bn >> 4;
    const int bx = bn & 15;

    f32x4 accH[4][4] = {};
    f32x4 accX[4][4] = {};
    uint4 Wh0, Wh1, Wl0, Wl1;

    auto stageA = [&](int s, int cur) {
        const ushort* src = Ag + (long)(mb * 64 + s) * 10240;
        ushort* dst = &A2[cur][0][0];
        #pragma unroll
        for (int i = 0; i < 5; ++i)
            gld_lds16(src + (i * 256 + t) * 8, dst + (i * 256 + t) * 8);
    };
    auto loadB = [&](int s) {
        int ab = s >> 2;
        int a = ab >> 2, b = ab & 3, c0 = (s & 3) * 32;
        const ushort* src = d2p
            + ((long)(ny0 + bdy + a) * 148 + (nx0 + bx + b)) * 256 + c0 + bh * 16;
        Wh0 = *(const uint4*)src;
        Wh1 = *(const uint4*)(src + 8);
        Wl0 = *(const uint4*)(src + 128);
        Wl1 = *(const uint4*)(src + 136);
    };
    auto writeB = [&](int cur) {
        int ro = bn * 40 + bh * 16;
        ushort* dh = &B2[cur][0][0] + ro;
        ushort* dl = &B2[cur][1][0] + ro;
        *(uint4*)dh = Wh0;
        *(uint4*)(dh + 8) = Wh1;
        *(uint4*)dl = Wl0;
        *(uint4*)(dl + 8) = Wl1;
    };

    // prologue: stage step 0
    stageA(0, 0);
    loadB(0);
    writeB(0);
    __syncthreads();   // drains vmcnt (A DMA) + lgkm (B writes)

    for (int s = 0; s < 64; ++s) {
        const int cur = s & 1;
        if (s < 63) { stageA(s + 1, cur ^ 1); loadB(s + 1); }  // issue early (T14)

        f16x8 fah[4], fal[4];
        #pragma unroll
        for (int mi = 0; mi < 4; ++mi) {
            int ra = (wm * 64 + mi * 16 + lm) * 40 + lg * 8;
            fah[mi] = *(const f16x8*)(&A2[cur][0][0] + ra);
            fal[mi] = *(const f16x8*)(&A2[cur][1][0] + ra);
        }
        #pragma unroll
        for (int ni = 0; ni < 4; ++ni) {
            int rb = (wn_ * 64 + ni * 16 + lm) * 40 + lg * 8;
            f16x8 fbh = *(const f16x8*)(&B2[cur][0][0] + rb);
            f16x8 fbl = *(const f16x8*)(&B2[cur][1][0] + rb);
            #pragma unroll
            for (int mi = 0; mi < 4; ++mi) {
                accH[mi][ni] = __builtin_amdgcn_mfma_f32_16x16x32_f16(fah[mi], fbh, accH[mi][ni], 0, 0, 0);
                accX[mi][ni] = __builtin_amdgcn_mfma_f32_16x16x32_f16(fah[mi], fbl, accX[mi][ni], 0, 0, 0);
                accX[mi][ni] = __builtin_amdgcn_mfma_f32_16x16x32_f16(fal[mi], fbh, accX[mi][ni], 0, 0, 0);
            }
        }

        if (s < 63) writeB(cur ^ 1);   // write late, into the other buffer
        __syncthreads();               // one barrier per step
    }

    // epilogue: combine, normalize, activate, store
    #pragma unroll
    for (int mi = 0; mi < 4; ++mi) {
        #pragma unroll
        for (int ni = 0; ni < 4; ++ni) {
            int y = ny0 + wn_ * 4 + ni;
            int x = nx0 + lm;
            if (y < HO && x < HO) {
                float wv = wnorm[y * HO + x];
                f32x4 vh = accH[mi][ni];
                f32x4 vx = accX[mi][ni];
                #pragma unroll
                for (int r = 0; r < 4; ++r) {
                    int p = p0 + wm * 64 + mi * 16 + lg * 4 + r;
                    float num = vh[r] + vx[r] * (1.0f / 2048.0f);
                    float c = num / (pn[p] * wv + EPSF);
                    out[(long)p * (HO * HO) + y * HO + x] = activate(c);
                }
            }
        }
    }
}

// ---------------- pyramid device bodies ----------------
__device__ __forceinline__ void maxpool_body(const float* __restrict__ in,
                                             float* __restrict__ out,
                                             int idx, int h, int hp) {
    int s = idx % hp;
    int r = (idx / hp) % hp;
    int g = idx / (hp * hp);
    const float* base = in + (long)g * h * h;
    int y0 = 2 * r - 1, x0 = 2 * s - 1;
    float m = -1e30f;
    #pragma unroll
    for (int dy = 0; dy < 3; ++dy) {
        int y = y0 + dy;
        if ((unsigned)y >= (unsigned)h) continue;
        #pragma unroll
        for (int dx = 0; dx < 3; ++dx) {
            int x = x0 + dx;
            if ((unsigned)x >= (unsigned)h) continue;
            m = fmaxf(m, base[y * h + x]);
        }
    }
    out[idx] = m;
}

__device__ __forceinline__ void sparse_body(const float* __restrict__ pooled,
                                            float* __restrict__ out,
                                            int idx, int G2, int h) {
    int x = idx % h;
    int y = (idx / h) % h;
    int J = (idx / (h * h)) % G2;
    int I = idx / (h * h * G2);
    int G = 2 * G2;
    float s = 0.f;
    #pragma unroll
    for (int di = 0; di < 2; ++di) {
        int yy = y + 1 - 2 * di;
        if ((unsigned)yy >= (unsigned)h) continue;
        #pragma unroll
        for (int dj = 0; dj < 2; ++dj) {
            int xx = x + 1 - 2 * dj;
            if ((unsigned)xx >= (unsigned)h) continue;
            s += pooled[((((2 * I + di) * G) + (2 * J + dj)) * (long)h + yy) * h + xx];
        }
    }
    out[idx] = activate(0.25f * s);
}

__device__ __forceinline__ void unpool_body(float* __restrict__ lo,
                                            const float* __restrict__ pooled,
                                            const float* __restrict__ up,
                                            int idx, int G, int hl, int hp) {
    int x = idx % hl;
    int y = (idx / hl) % hl;
    int gj = (idx / (hl * hl)) % G;
    int gi = idx / (hl * hl * G);
    float l = lo[idx];
    float m = pooled[(((long)gi * G + gj) * hp + (y >> 1)) * hp + (x >> 1)];
    if (l == m) {
        int ry = (y >> 1) - 1 + 2 * (gi & 1);
        int rx = (x >> 1) - 1 + 2 * (gj & 1);
        float uv = 0.f;
        if ((unsigned)ry < (unsigned)hp && (unsigned)rx < (unsigned)hp)
            uv = up[((((long)(gi >> 1)) * (G >> 1) + (gj >> 1)) * hp + ry) * hp + rx];
        lo[idx] = fmaxf(l, uv);
    }
}

// ---------------- standalone pyramid kernels (big levels) ----------------
__global__ void maxpool_k(const float* __restrict__ in, float* __restrict__ out,
                          int GG, int h, int hp) {
    int idx = blockIdx.x * 256 + threadIdx.x;
    if (idx >= GG * hp * hp) return;
    maxpool_body(in, out, idx, h, hp);
}

__global__ void sparse_fwd_k(const float* __restrict__ pooled, float* __restrict__ out,
                             int G2, int h) {
    int idx = blockIdx.x * 256 + threadIdx.x;
    if (idx >= G2 * G2 * h * h) return;
    sparse_body(pooled, out, idx, G2, h);
}

__global__ void unpool_k(float* __restrict__ lo, const float* __restrict__ pooled,
                         const float* __restrict__ up, int G, int hl, int hp) {
    int idx = blockIdx.x * 256 + threadIdx.x;
    if (idx >= G * G * hl * hl) return;
    unpool_body(lo, pooled, up, idx, G, hl, hp);
}

// ---------------- fused small levels (3..5 fwd + unpool 5->4->3->2), 1 block ----------------
__global__ void small_levels(float* __restrict__ pyr2,
                             float* __restrict__ pool3, float* __restrict__ pyr3,
                             float* __restrict__ pool4, float* __restrict__ pyr4,
                             float* __restrict__ pool5, float* __restrict__ pyr5)
{
    const int t = threadIdx.x;
    for (int i = t; i < 64 * 17 * 17; i += 1024) maxpool_body(pyr2, pool3, i, 33, 17);
    __syncthreads();
    for (int i = t; i < 16 * 17 * 17; i += 1024) sparse_body(pool3, pyr3, i, 4, 17);
    __syncthreads();
    for (int i = t; i < 16 * 9 * 9; i += 1024) maxpool_body(pyr3, pool4, i, 17, 9);
    __syncthreads();
    for (int i = t; i < 4 * 9 * 9; i += 1024) sparse_body(pool4, pyr4, i, 2, 9);
    __syncthreads();
    for (int i = t; i < 4 * 5 * 5; i += 1024) maxpool_body(pyr4, pool5, i, 9, 5);
    __syncthreads();
    for (int i = t; i < 5 * 5; i += 1024) sparse_body(pool5, pyr5, i, 1, 5);
    __syncthreads();
    for (int i = t; i < 4 * 9 * 9; i += 1024) unpool_body(pyr4, pool5, pyr5, i, 2, 9, 5);
    __syncthreads();
    for (int i = t; i < 16 * 17 * 17; i += 1024) unpool_body(pyr3, pool4, pyr4, i, 4, 17, 9);
    __syncthreads();
    for (int i = t; i < 64 * 33 * 33; i += 1024) unpool_body(pyr2, pool3, pyr3, i, 8, 33, 17);
}

// ---------------- workspace layout (floats) ----------------
// d2p: 140*148*2*128 = 5,304,320 ushorts = 2,652,160 floats
// Ag:  8*64*2*128*40 = 5,242,880 ushorts = 2,621,440 floats
#define PN_OFF    0L
#define WN_OFF    1024L
#define SQ_OFF    17728L
#define CBASE     34112L
#define D2P_OFF   (CBASE)                  // [CBASE, CBASE+2,652,160)
#define AG_OFF    (CBASE + 2652160L)       // [.., CBASE+5,273,600)
// pyramid phase (aliases conv-phase buffers; disjoint in time):
#define POOL1_OFF (CBASE)                  // 4,326,400
#define PYR1_OFF  (CBASE + 4326400L)       // 1,081,600
#define POOL2_OFF (CBASE + 5408000L)       // 278,784
#define PYR2_OFF  (CBASE + 5686784L)       // 69,696
#define POOL3_OFF (CBASE + 5756480L)       // 18,496
#define PYR3_OFF  (CBASE + 5774976L)       // 4,624
#define POOL4_OFF (CBASE + 5779600L)       // 1,296
#define PYR4_OFF  (CBASE + 5780896L)       // 324
#define POOL5_OFF (CBASE + 5781220L)       // 100
#define PYR5_OFF  (CBASE + 5781320L)       // 25

extern "C" void kernel_launch(void* const* d_in, const int* in_sizes, int n_in,
                              void* d_out, int out_size, void* d_ws, size_t ws_size,
                              hipStream_t stream) {
    const float* d1 = (const float*)d_in[0];
    const float* d2 = (const float*)d_in[1];
    float* out = (float*)d_out;
    float* ws = (float*)d_ws;

    float* pnf   = ws + PN_OFF;
    float* wnf   = ws + WN_OFF;
    float* sqf   = ws + SQ_OFF;
    ushort* d2p  = (ushort*)(ws + D2P_OFF);
    ushort* Ag   = (ushort*)(ws + AG_OFF);
    float* pool1 = ws + POOL1_OFF;
    float* pyr1  = ws + PYR1_OFF;
    float* pool2 = ws + POOL2_OFF;
    float* pyr2  = ws + PYR2_OFF;
    float* pool3 = ws + POOL3_OFF;
    float* pyr3  = ws + PYR3_OFF;
    float* pool4 = ws + POOL4_OFF;
    float* pyr4  = ws + PYR4_OFF;
    float* pool5 = ws + POOL5_OFF;
    float* pyr5  = ws + PYR5_OFF;

    // prep
    prep_d2<<<(140 * 148 * 128 + 255) / 256, 256, 0, stream>>>(d2, d2p);
    build_Afrag<<<(8 * 64 * 2 * 128 * 40 + 255) / 256, 256, 0, stream>>>(d1, Ag);
    pnorm_k<<<1024, 64, 0, stream>>>(d1, pnf);
    sq_k<<<64, 256, 0, stream>>>(d2, sqf);
    wnorm_k<<<(HO * HO + 255) / 256, 256, 0, stream>>>(sqf, wnf);

    // correlation GEMM (MFMA) + normalize + activation -> pyramid0 in d_out
    conv_mfma<<<8 * 153, 256, 0, stream>>>(Ag, d2p, pnf, wnf, out);

    // forward pyramid, levels 0->2 (big)
    maxpool_k<<<(1024 * 65 * 65 + 255) / 256, 256, 0, stream>>>(out, pool1, 1024, 129, 65);
    sparse_fwd_k<<<(256 * 65 * 65 + 255) / 256, 256, 0, stream>>>(pool1, pyr1, 16, 65);
    maxpool_k<<<(256 * 33 * 33 + 255) / 256, 256, 0, stream>>>(pyr1, pool2, 256, 65, 33);
    sparse_fwd_k<<<(64 * 33 * 33 + 255) / 256, 256, 0, stream>>>(pool2, pyr2, 8, 33);

    // fused small levels: mp3..sf5 + unpool 5->4->3->2 (updates pyr2 in place)
    small_levels<<<1, 1024, 0, stream>>>(pyr2, pool3, pyr3, pool4, pyr4, pool5, pyr5);

    // remaining unpool chain
    unpool_k<<<(256 * 4225 + 255) / 256, 256, 0, stream>>>(pyr1, pool2, pyr2, 16, 65, 33);
    unpool_k<<<(1024 * 16641 + 255) / 256, 256, 0, stream>>>(out, pool1, pyr1, 32, 129, 65);
}

// Round 7
// 568.658 us; speedup vs baseline: 1.0306x; 1.0306x over previous
//
#include <hip/hip_runtime.h>
#include <hip/hip_fp16.h>
#include <math.h>

typedef unsigned int uint;
typedef unsigned short ushort;
typedef short f16x8 __attribute__((ext_vector_type(8)));
typedef float f32x4 __attribute__((ext_vector_type(4)));

#define NLPOW 1.4f
#define EPSF 1e-8f
#define HO 129

__device__ __forceinline__ float activate(float c) {
    c = fmaxf(c, 0.0f);
    return powf(c, NLPOW);
}

// f16 split with scaled residual: v ~= h + l/2048 (h,l = f16 bit patterns)
__device__ __forceinline__ void f16split(float v, ushort& h, ushort& l) {
    __half hv = __float2half(v);           // RNE
    h = __half_as_ushort(hv);
    float r = (v - __half2float(hv)) * 2048.0f;
    l = __half_as_ushort(__float2half(r));
}

__device__ __forceinline__ void gld_lds16(const ushort* g, ushort* l) {
    __builtin_amdgcn_global_load_lds(
        (const __attribute__((address_space(1))) void*)g,
        (__attribute__((address_space(3))) void*)l,
        16, 0, 0);
}

// ---------------- prep: padded channel-last f16-split of desc2 ----------------
// d2p[yp:140][xp:148][plane:2][c:128] ushort; plane0 = h, plane1 = l (scaled residual)
__global__ void prep_d2(const float* __restrict__ d2, ushort* __restrict__ d2p) {
    int idx = blockIdx.x * 256 + threadIdx.x;
    if (idx >= 140 * 148 * 128) return;
    int c = idx & 127;
    int xp = (idx >> 7) % 148;
    int yp = idx / (148 * 128);
    int y = yp - 2, x = xp - 2;
    float v = 0.f;
    if ((unsigned)y < 128u && (unsigned)x < 128u)
        v = d2[c * 16384 + y * 128 + x];
    ushort h, lo;
    f16split(v, h, lo);
    long o = ((long)(yp * 148 + xp)) * 256 + c;
    d2p[o] = h;
    d2p[o + 128] = lo;
}

// ---------------- prep: A in linear LDS-image layout, stride 40 ----------------
// Ag[mb][s][plane:2][128 rows][40 kk] ushort (kk<32 valid); k' = s*32+kk = (a*4+b)*128 + c
__global__ void build_Afrag(const float* __restrict__ d1, ushort* __restrict__ Ag) {
    int idx = blockIdx.x * 256 + threadIdx.x;
    if (idx >= 8 * 64 * 2 * 128 * 40) return;
    int kk = idx % 40;
    int row = (idx / 40) % 128;
    int pl = (idx / 5120) % 2;
    int s = (idx / 10240) % 64;
    int mb = idx / 655360;
    ushort hv = 0, lv = 0;
    if (kk < 32) {
        int kp = s * 32 + kk;
        int c = kp & 127;
        int ab = kp >> 7;
        int a = ab >> 2, b = ab & 3;
        int p = mb * 128 + row;
        int i = p >> 5, j = p & 31;
        float v = d1[c * 16384 + (4 * i + a) * 128 + (4 * j + b)];
        f16split(v, hv, lv);
    }
    Ag[idx] = pl ? lv : hv;
}

// ---------------- pnorm[p] from d1 directly ----------------
__global__ void pnorm_k(const float* __restrict__ d1, float* __restrict__ pn) {
    int p = blockIdx.x;
    int t = threadIdx.x;
    int i = p >> 5, j = p & 31;
    int pix = t & 15;
    int a = pix >> 2, b = pix & 3;
    int cg = t >> 4;
    const float* base = d1 + (4 * i + a) * 128 + (4 * j + b);
    float s = 0.f;
    for (int c = cg * 32; c < cg * 32 + 32; ++c) {
        float v = base[c * 16384];
        s += v * v;
    }
    #pragma unroll
    for (int off = 32; off > 0; off >>= 1) s += __shfl_down(s, off);
    if (t == 0) pn[p] = sqrtf(s);
}

// ---------------- sq[y][x] = sum_c desc2^2 ----------------
__global__ void sq_k(const float* __restrict__ d2, float* __restrict__ sq) {
    int idx = blockIdx.x * 256 + threadIdx.x;
    if (idx >= 16384) return;
    float s = 0.f;
    for (int c = 0; c < 128; ++c) {
        float v = d2[c * 16384 + idx];
        s += v * v;
    }
    sq[idx] = s;
}

// ---------------- wnorm ----------------
__global__ void wnorm_k(const float* __restrict__ sq, float* __restrict__ wnorm) {
    int idx = blockIdx.x * 256 + threadIdx.x;
    if (idx >= HO * HO) return;
    int y = idx / HO, x = idx % HO;
    float s = 0.f;
    #pragma unroll
    for (int a = 0; a < 4; ++a) {
        int yy = y - 2 + a;
        if ((unsigned)yy >= 128u) continue;
        #pragma unroll
        for (int b = 0; b < 4; ++b) {
            int xx = x - 2 + b;
            if ((unsigned)xx >= 128u) continue;
            s += sq[yy * 128 + xx];
        }
    }
    wnorm[idx] = sqrtf(s);
}

// ---------------- main correlation: f16-split 3-stream MFMA implicit GEMM ----------------
// M=1024, N=129x129 (tiled 8y x 16x), K=2048 over 64 steps of 32.
// corr = accH + accX/2048. XCD-pinned mb. LDS 81920 B -> 2 blocks/CU.
// x4-unrolled loop: cur & (s&3) compile-time -> frag reads/writes are
// base-VGPR + literal-offset (zero per-step VALU); DMA src via pointer bump.
__global__ __launch_bounds__(256, 2) void conv_mfma(
    const ushort* __restrict__ Ag,     // [mb][s][2][128][40]
    const ushort* __restrict__ d2p,    // [140][148][2][128] f16 channel-last h/l
    const float* __restrict__ pn, const float* __restrict__ wnorm,
    float* __restrict__ out)
{
    __shared__ __align__(16) ushort A2[2][2][5120];   // [buf][plane][row*40]
    __shared__ __align__(16) ushort B2[2][2][5120];

    const int t = threadIdx.x;
    const int mb = blockIdx.x & 7;        // XCD-pinned M-panel
    const int nb = blockIdx.x >> 3;       // 0..152
    const int ny0 = (nb / 9) * 8;
    const int nx0 = (nb % 9) * 16;
    const int p0 = mb * 128;

    const int l = t & 63;
    const int w = t >> 6;
    const int wm = w & 1, wn_ = w >> 1;
    const int lm = l & 15, lg = l >> 4;

    // B staging mapping: row n = t>>1 (y=n>>4, x=n&15), half = t&1 (16 channels)
    const int bn = t >> 1;
    const int bh = t & 1;
    const int bdy = bn >> 4;
    const int bx = bn & 15;

    f32x4 accH[4][4] = {};
    f32x4 accX[4][4] = {};
    uint4 Wh0, Wh1, Wl0, Wl1;

    // ---- thread-invariant base pointers (computed once) ----
    const ushort* aSrcT = Ag + (long)mb * 64 * 10240 + t * 8;            // A DMA source
    ushort* aDstT = &A2[0][0][0] + t * 8;                                 // A DMA dest
    const ushort* bT = d2p + ((long)(ny0 + bdy) * 148 + (nx0 + bx)) * 256 + bh * 16;
    ushort* bW = &B2[0][0][0] + bn * 40 + bh * 16;                        // B write base
    const ushort* aBase = &A2[0][0][0] + (wm * 64 + lm) * 40 + lg * 8;    // A frag base
    const ushort* bBase = &B2[0][0][0] + (wn_ * 64 + lm) * 40 + lg * 8;   // B frag base

    // ---- prologue: stage step 0 into buf 0 ----
    #pragma unroll
    for (int i = 0; i < 5; ++i)
        gld_lds16(aSrcT + i * 2048, aDstT + i * 2048);
    Wh0 = *(const uint4*)bT;
    Wh1 = *(const uint4*)(bT + 8);
    Wl0 = *(const uint4*)(bT + 128);
    Wl1 = *(const uint4*)(bT + 136);
    *(uint4*)bW = Wh0;
    *(uint4*)(bW + 8) = Wh1;
    *(uint4*)(bW + 5120) = Wl0;
    *(uint4*)(bW + 5128) = Wl1;
    __syncthreads();   // drains vmcnt (A DMA) + lgkm (B writes)

    const ushort* aStage = aSrcT + 10240;   // DMA source for step 1

    for (int s4 = 0; s4 < 64; s4 += 4) {
        #pragma unroll
        for (int p = 0; p < 4; ++p) {
            const int s = s4 + p;          // p compile-time, s4 uniform
            const int cur = p & 1;

            // ---- stage s+1 (issue early; completes under MFMA) ----
            if (s < 63) {
                // A: DMA into buf cur^1 (literal phase offsets off bumped ptr)
                #pragma unroll
                for (int i = 0; i < 5; ++i)
                    gld_lds16(aStage + p * 10240 + i * 2048,
                              aDstT + (cur ^ 1) * 10240 + i * 2048);
                // B: global -> regs for s+1 (uniform offset, SALU)
                const int sn = s + 1;
                const int ab = sn >> 2;
                const int uoff = ((ab >> 2) * 148 + (ab & 3)) * 256 + (sn & 3) * 32;
                const ushort* src = bT + uoff;
                Wh0 = *(const uint4*)src;
                Wh1 = *(const uint4*)(src + 8);
                Wl0 = *(const uint4*)(src + 128);
                Wl1 = *(const uint4*)(src + 136);
            }

            // ---- frag reads from buf cur (base VGPR + literal offsets) ----
            f16x8 fah[4], fal[4];
            #pragma unroll
            for (int mi = 0; mi < 4; ++mi) {
                fah[mi] = *(const f16x8*)(aBase + cur * 10240 + mi * 640);
                fal[mi] = *(const f16x8*)(aBase + cur * 10240 + 5120 + mi * 640);
            }
            #pragma unroll
            for (int ni = 0; ni < 4; ++ni) {
                f16x8 fbh = *(const f16x8*)(bBase + cur * 10240 + ni * 640);
                f16x8 fbl = *(const f16x8*)(bBase + cur * 10240 + 5120 + ni * 640);
                #pragma unroll
                for (int mi = 0; mi < 4; ++mi) {
                    accH[mi][ni] = __builtin_amdgcn_mfma_f32_16x16x32_f16(fah[mi], fbh, accH[mi][ni], 0, 0, 0);
                    accX[mi][ni] = __builtin_amdgcn_mfma_f32_16x16x32_f16(fah[mi], fbl, accX[mi][ni], 0, 0, 0);
                    accX[mi][ni] = __builtin_amdgcn_mfma_f32_16x16x32_f16(fal[mi], fbh, accX[mi][ni], 0, 0, 0);
                }
            }

            // ---- write B(s+1) into buf cur^1 (zero VALU) ----
            if (s < 63) {
                ushort* dh = bW + (cur ^ 1) * 10240;
                *(uint4*)dh = Wh0;
                *(uint4*)(dh + 8) = Wh1;
                *(uint4*)(dh + 5120) = Wl0;
                *(uint4*)(dh + 5128) = Wl1;
            }
            __syncthreads();               // one barrier per step
        }
        aStage += 40960;                   // 4 steps' worth of A source
    }

    // ---- epilogue: combine, normalize, activate, store ----
    #pragma unroll
    for (int mi = 0; mi < 4; ++mi) {
        #pragma unroll
        for (int ni = 0; ni < 4; ++ni) {
            int y = ny0 + wn_ * 4 + ni;
            int x = nx0 + lm;
            if (y < HO && x < HO) {
                float wv = wnorm[y * HO + x];
                f32x4 vh = accH[mi][ni];
                f32x4 vx = accX[mi][ni];
                #pragma unroll
                for (int r = 0; r < 4; ++r) {
                    int p = p0 + wm * 64 + mi * 16 + lg * 4 + r;
                    float num = vh[r] + vx[r] * (1.0f / 2048.0f);
                    float c = num / (pn[p] * wv + EPSF);
                    out[(long)p * (HO * HO) + y * HO + x] = activate(c);
                }
            }
        }
    }
}

// ---------------- pyramid device bodies ----------------
__device__ __forceinline__ void maxpool_body(const float* __restrict__ in,
                                             float* __restrict__ out,
                                             int idx, int h, int hp) {
    int s = idx % hp;
    int r = (idx / hp) % hp;
    int g = idx / (hp * hp);
    const float* base = in + (long)g * h * h;
    int y0 = 2 * r - 1, x0 = 2 * s - 1;
    float m = -1e30f;
    #pragma unroll
    for (int dy = 0; dy < 3; ++dy) {
        int y = y0 + dy;
        if ((unsigned)y >= (unsigned)h) continue;
        #pragma unroll
        for (int dx = 0; dx < 3; ++dx) {
            int x = x0 + dx;
            if ((unsigned)x >= (unsigned)h) continue;
            m = fmaxf(m, base[y * h + x]);
        }
    }
    out[idx] = m;
}

__device__ __forceinline__ void sparse_body(const float* __restrict__ pooled,
                                            float* __restrict__ out,
                                            int idx, int G2, int h) {
    int x = idx % h;
    int y = (idx / h) % h;
    int J = (idx / (h * h)) % G2;
    int I = idx / (h * h * G2);
    int G = 2 * G2;
    float s = 0.f;
    #pragma unroll
    for (int di = 0; di < 2; ++di) {
        int yy = y + 1 - 2 * di;
        if ((unsigned)yy >= (unsigned)h) continue;
        #pragma unroll
        for (int dj = 0; dj < 2; ++dj) {
            int xx = x + 1 - 2 * dj;
            if ((unsigned)xx >= (unsigned)h) continue;
            s += pooled[((((2 * I + di) * G) + (2 * J + dj)) * (long)h + yy) * h + xx];
        }
    }
    out[idx] = activate(0.25f * s);
}

__device__ __forceinline__ void unpool_body(float* __restrict__ lo,
                                            const float* __restrict__ pooled,
                                            const float* __restrict__ up,
                                            int idx, int G, int hl, int hp) {
    int x = idx % hl;
    int y = (idx / hl) % hl;
    int gj = (idx / (hl * hl)) % G;
    int gi = idx / (hl * hl * G);
    float l = lo[idx];
    float m = pooled[(((long)gi * G + gj) * hp + (y >> 1)) * hp + (x >> 1)];
    if (l == m) {
        int ry = (y >> 1) - 1 + 2 * (gi & 1);
        int rx = (x >> 1) - 1 + 2 * (gj & 1);
        float uv = 0.f;
        if ((unsigned)ry < (unsigned)hp && (unsigned)rx < (unsigned)hp)
            uv = up[((((long)(gi >> 1)) * (G >> 1) + (gj >> 1)) * hp + ry) * hp + rx];
        lo[idx] = fmaxf(l, uv);
    }
}

// ---------------- standalone pyramid kernels (big levels) ----------------
__global__ void maxpool_k(const float* __restrict__ in, float* __restrict__ out,
                          int GG, int h, int hp) {
    int idx = blockIdx.x * 256 + threadIdx.x;
    if (idx >= GG * hp * hp) return;
    maxpool_body(in, out, idx, h, hp);
}

__global__ void sparse_fwd_k(const float* __restrict__ pooled, float* __restrict__ out,
                             int G2, int h) {
    int idx = blockIdx.x * 256 + threadIdx.x;
    if (idx >= G2 * G2 * h * h) return;
    sparse_body(pooled, out, idx, G2, h);
}

__global__ void unpool_k(float* __restrict__ lo, const float* __restrict__ pooled,
                         const float* __restrict__ up, int G, int hl, int hp) {
    int idx = blockIdx.x * 256 + threadIdx.x;
    if (idx >= G * G * hl * hl) return;
    unpool_body(lo, pooled, up, idx, G, hl, hp);
}

// ---------------- fused small levels (3..5 fwd + unpool 5->4->3->2), 1 block ----------------
__global__ void small_levels(float* __restrict__ pyr2,
                             float* __restrict__ pool3, float* __restrict__ pyr3,
                             float* __restrict__ pool4, float* __restrict__ pyr4,
                             float* __restrict__ pool5, float* __restrict__ pyr5)
{
    const int t = threadIdx.x;
    for (int i = t; i < 64 * 17 * 17; i += 1024) maxpool_body(pyr2, pool3, i, 33, 17);
    __syncthreads();
    for (int i = t; i < 16 * 17 * 17; i += 1024) sparse_body(pool3, pyr3, i, 4, 17);
    __syncthreads();
    for (int i = t; i < 16 * 9 * 9; i += 1024) maxpool_body(pyr3, pool4, i, 17, 9);
    __syncthreads();
    for (int i = t; i < 4 * 9 * 9; i += 1024) sparse_body(pool4, pyr4, i, 2, 9);
    __syncthreads();
    for (int i = t; i < 4 * 5 * 5; i += 1024) maxpool_body(pyr4, pool5, i, 9, 5);
    __syncthreads();
    for (int i = t; i < 5 * 5; i += 1024) sparse_body(pool5, pyr5, i, 1, 5);
    __syncthreads();
    for (int i = t; i < 4 * 9 * 9; i += 1024) unpool_body(pyr4, pool5, pyr5, i, 2, 9, 5);
    __syncthreads();
    for (int i = t; i < 16 * 17 * 17; i += 1024) unpool_body(pyr3, pool4, pyr4, i, 4, 17, 9);
    __syncthreads();
    for (int i = t; i < 64 * 33 * 33; i += 1024) unpool_body(pyr2, pool3, pyr3, i, 8, 33, 17);
}

// ---------------- workspace layout (floats) ----------------
// d2p: 140*148*2*128 = 5,304,320 ushorts = 2,652,160 floats
// Ag:  8*64*2*128*40 = 5,242,880 ushorts = 2,621,440 floats
#define PN_OFF    0L
#define WN_OFF    1024L
#define SQ_OFF    17728L
#define CBASE     34112L
#define D2P_OFF   (CBASE)                  // [CBASE, CBASE+2,652,160)
#define AG_OFF    (CBASE + 2652160L)       // [.., CBASE+5,273,600)
// pyramid phase (aliases conv-phase buffers; disjoint in time):
#define POOL1_OFF (CBASE)                  // 4,326,400
#define PYR1_OFF  (CBASE + 4326400L)       // 1,081,600
#define POOL2_OFF (CBASE + 5408000L)       // 278,784
#define PYR2_OFF  (CBASE + 5686784L)       // 69,696
#define POOL3_OFF (CBASE + 5756480L)       // 18,496
#define PYR3_OFF  (CBASE + 5774976L)       // 4,624
#define POOL4_OFF (CBASE + 5779600L)       // 1,296
#define PYR4_OFF  (CBASE + 5780896L)       // 324
#define POOL5_OFF (CBASE + 5781220L)       // 100
#define PYR5_OFF  (CBASE + 5781320L)       // 25

extern "C" void kernel_launch(void* const* d_in, const int* in_sizes, int n_in,
                              void* d_out, int out_size, void* d_ws, size_t ws_size,
                              hipStream_t stream) {
    const float* d1 = (const float*)d_in[0];
    const float* d2 = (const float*)d_in[1];
    float* out = (float*)d_out;
    float* ws = (float*)d_ws;

    float* pnf   = ws + PN_OFF;
    float* wnf   = ws + WN_OFF;
    float* sqf   = ws + SQ_OFF;
    ushort* d2p  = (ushort*)(ws + D2P_OFF);
    ushort* Ag   = (ushort*)(ws + AG_OFF);
    float* pool1 = ws + POOL1_OFF;
    float* pyr1  = ws + PYR1_OFF;
    float* pool2 = ws + POOL2_OFF;
    float* pyr2  = ws + PYR2_OFF;
    float* pool3 = ws + POOL3_OFF;
    float* pyr3  = ws + PYR3_OFF;
    float* pool4 = ws + POOL4_OFF;
    float* pyr4  = ws + PYR4_OFF;
    float* pool5 = ws + POOL5_OFF;
    float* pyr5  = ws + PYR5_OFF;

    // prep
    prep_d2<<<(140 * 148 * 128 + 255) / 256, 256, 0, stream>>>(d2, d2p);
    build_Afrag<<<(8 * 64 * 2 * 128 * 40 + 255) / 256, 256, 0, stream>>>(d1, Ag);
    pnorm_k<<<1024, 64, 0, stream>>>(d1, pnf);
    sq_k<<<64, 256, 0, stream>>>(d2, sqf);
    wnorm_k<<<(HO * HO + 255) / 256, 256, 0, stream>>>(sqf, wnf);

    // correlation GEMM (MFMA) + normalize + activation -> pyramid0 in d_out
    conv_mfma<<<8 * 153, 256, 0, stream>>>(Ag, d2p, pnf, wnf, out);

    // forward pyramid, levels 0->2 (big)
    maxpool_k<<<(1024 * 65 * 65 + 255) / 256, 256, 0, stream>>>(out, pool1, 1024, 129, 65);
    sparse_fwd_k<<<(256 * 65 * 65 + 255) / 256, 256, 0, stream>>>(pool1, pyr1, 16, 65);
    maxpool_k<<<(256 * 33 * 33 + 255) / 256, 256, 0, stream>>>(pyr1, pool2, 256, 65, 33);
    sparse_fwd_k<<<(64 * 33 * 33 + 255) / 256, 256, 0, stream>>>(pool2, pyr2, 8, 33);

    // fused small levels: mp3..sf5 + unpool 5->4->3->2 (updates pyr2 in place)
    small_levels<<<1, 1024, 0, stream>>>(pyr2, pool3, pyr3, pool4, pyr4, pool5, pyr5);

    // remaining unpool chain
    unpool_k<<<(256 * 4225 + 255) / 256, 256, 0, stream>>>(pyr1, pool2, pyr2, 16, 65, 33);
    unpool_k<<<(1024 * 16641 + 255) / 256, 256, 0, stream>>>(out, pool1, pyr1, 32, 129, 65);
}

// Round 8
// 567.421 us; speedup vs baseline: 1.0329x; 1.0022x over previous
//
#include <hip/hip_runtime.h>
#include <hip/hip_fp16.h>
#include <math.h>

typedef unsigned int uint;
typedef unsigned short ushort;
typedef short f16x8 __attribute__((ext_vector_type(8)));
typedef float f32x4 __attribute__((ext_vector_type(4)));

#define NLPOW 1.4f
#define EPSF 1e-8f
#define HO 129

__device__ __forceinline__ float activate(float c) {
    c = fmaxf(c, 0.0f);
    return powf(c, NLPOW);
}

// f16 split with scaled residual: v ~= h + l/2048 (h,l = f16 bit patterns)
__device__ __forceinline__ void f16split(float v, ushort& h, ushort& l) {
    __half hv = __float2half(v);           // RNE
    h = __half_as_ushort(hv);
    float r = (v - __half2float(hv)) * 2048.0f;
    l = __half_as_ushort(__float2half(r));
}

__device__ __forceinline__ void gld_lds16(const ushort* g, ushort* l) {
    __builtin_amdgcn_global_load_lds(
        (const __attribute__((address_space(1))) void*)g,
        (__attribute__((address_space(3))) void*)l,
        16, 0, 0);
}

// ---------------- prep: padded channel-last f16-split of desc2 ----------------
// d2p[yp:140][xp:148][plane:2][c:128] ushort; plane0 = h, plane1 = l (scaled residual)
__global__ void prep_d2(const float* __restrict__ d2, ushort* __restrict__ d2p) {
    int idx = blockIdx.x * 256 + threadIdx.x;
    if (idx >= 140 * 148 * 128) return;
    int c = idx & 127;
    int xp = (idx >> 7) % 148;
    int yp = idx / (148 * 128);
    int y = yp - 2, x = xp - 2;
    float v = 0.f;
    if ((unsigned)y < 128u && (unsigned)x < 128u)
        v = d2[c * 16384 + y * 128 + x];
    ushort h, lo;
    f16split(v, h, lo);
    long o = ((long)(yp * 148 + xp)) * 256 + c;
    d2p[o] = h;
    d2p[o + 128] = lo;
}

// ---------------- prep: A in linear LDS-image layout, stride 40 ----------------
// Ag[mb][s][plane:2][128 rows][40 kk] ushort (kk<32 valid); k' = s*32+kk = (a*4+b)*128 + c
__global__ void build_Afrag(const float* __restrict__ d1, ushort* __restrict__ Ag) {
    int idx = blockIdx.x * 256 + threadIdx.x;
    if (idx >= 8 * 64 * 2 * 128 * 40) return;
    int kk = idx % 40;
    int row = (idx / 40) % 128;
    int pl = (idx / 5120) % 2;
    int s = (idx / 10240) % 64;
    int mb = idx / 655360;
    ushort hv = 0, lv = 0;
    if (kk < 32) {
        int kp = s * 32 + kk;
        int c = kp & 127;
        int ab = kp >> 7;
        int a = ab >> 2, b = ab & 3;
        int p = mb * 128 + row;
        int i = p >> 5, j = p & 31;
        float v = d1[c * 16384 + (4 * i + a) * 128 + (4 * j + b)];
        f16split(v, hv, lv);
    }
    Ag[idx] = pl ? lv : hv;
}

// ---------------- pnorm[p] from d1 directly ----------------
__global__ void pnorm_k(const float* __restrict__ d1, float* __restrict__ pn) {
    int p = blockIdx.x;
    int t = threadIdx.x;
    int i = p >> 5, j = p & 31;
    int pix = t & 15;
    int a = pix >> 2, b = pix & 3;
    int cg = t >> 4;
    const float* base = d1 + (4 * i + a) * 128 + (4 * j + b);
    float s = 0.f;
    for (int c = cg * 32; c < cg * 32 + 32; ++c) {
        float v = base[c * 16384];
        s += v * v;
    }
    #pragma unroll
    for (int off = 32; off > 0; off >>= 1) s += __shfl_down(s, off);
    if (t == 0) pn[p] = sqrtf(s);
}

// ---------------- sq[y][x] = sum_c desc2^2 ----------------
__global__ void sq_k(const float* __restrict__ d2, float* __restrict__ sq) {
    int idx = blockIdx.x * 256 + threadIdx.x;
    if (idx >= 16384) return;
    float s = 0.f;
    for (int c = 0; c < 128; ++c) {
        float v = d2[c * 16384 + idx];
        s += v * v;
    }
    sq[idx] = s;
}

// ---------------- wnorm ----------------
__global__ void wnorm_k(const float* __restrict__ sq, float* __restrict__ wnorm) {
    int idx = blockIdx.x * 256 + threadIdx.x;
    if (idx >= HO * HO) return;
    int y = idx / HO, x = idx % HO;
    float s = 0.f;
    #pragma unroll
    for (int a = 0; a < 4; ++a) {
        int yy = y - 2 + a;
        if ((unsigned)yy >= 128u) continue;
        #pragma unroll
        for (int b = 0; b < 4; ++b) {
            int xx = x - 2 + b;
            if ((unsigned)xx >= 128u) continue;
            s += sq[yy * 128 + xx];
        }
    }
    wnorm[idx] = sqrtf(s);
}

// ---------------- main correlation: f16-split 3-stream MFMA implicit GEMM ----------------
// M=1024, N=129x129 (tiled 8y x 16x), K=2048 over 64 steps of 32.
// corr = accH + accX/2048. XCD-pinned mb. LDS 81920 B -> 2 blocks/CU.
// x4-unrolled loop: cur & (s&3) compile-time -> frag reads/writes are
// base-VGPR + literal-offset (zero per-step VALU); DMA src via pointer bump.
__global__ __launch_bounds__(256, 2) void conv_mfma(
    const ushort* __restrict__ Ag,     // [mb][s][2][128][40]
    const ushort* __restrict__ d2p,    // [140][148][2][128] f16 channel-last h/l
    const float* __restrict__ pn, const float* __restrict__ wnorm,
    float* __restrict__ out)
{
    __shared__ __align__(16) ushort A2[2][2][5120];   // [buf][plane][row*40]
    __shared__ __align__(16) ushort B2[2][2][5120];

    const int t = threadIdx.x;
    const int mb = blockIdx.x & 7;        // XCD-pinned M-panel
    const int nb = blockIdx.x >> 3;       // 0..152
    const int ny0 = (nb / 9) * 8;
    const int nx0 = (nb % 9) * 16;
    const int p0 = mb * 128;

    const int l = t & 63;
    const int w = t >> 6;
    const int wm = w & 1, wn_ = w >> 1;
    const int lm = l & 15, lg = l >> 4;

    // B staging mapping: row n = t>>1 (y=n>>4, x=n&15), half = t&1 (16 channels)
    const int bn = t >> 1;
    const int bh = t & 1;
    const int bdy = bn >> 4;
    const int bx = bn & 15;

    f32x4 accH[4][4] = {};
    f32x4 accX[4][4] = {};
    uint4 Wh0, Wh1, Wl0, Wl1;

    // ---- thread-invariant base pointers (computed once) ----
    const ushort* aSrcT = Ag + (long)mb * 64 * 10240 + t * 8;            // A DMA source
    ushort* aDstT = &A2[0][0][0] + t * 8;                                 // A DMA dest
    const ushort* bT = d2p + ((long)(ny0 + bdy) * 148 + (nx0 + bx)) * 256 + bh * 16;
    ushort* bW = &B2[0][0][0] + bn * 40 + bh * 16;                        // B write base
    const ushort* aBase = &A2[0][0][0] + (wm * 64 + lm) * 40 + lg * 8;    // A frag base
    const ushort* bBase = &B2[0][0][0] + (wn_ * 64 + lm) * 40 + lg * 8;   // B frag base

    // ---- prologue: stage step 0 into buf 0 ----
    #pragma unroll
    for (int i = 0; i < 5; ++i)
        gld_lds16(aSrcT + i * 2048, aDstT + i * 2048);
    Wh0 = *(const uint4*)bT;
    Wh1 = *(const uint4*)(bT + 8);
    Wl0 = *(const uint4*)(bT + 128);
    Wl1 = *(const uint4*)(bT + 136);
    *(uint4*)bW = Wh0;
    *(uint4*)(bW + 8) = Wh1;
    *(uint4*)(bW + 5120) = Wl0;
    *(uint4*)(bW + 5128) = Wl1;
    __syncthreads();   // drains vmcnt (A DMA) + lgkm (B writes)

    const ushort* aStage = aSrcT + 10240;   // DMA source for step 1

    for (int s4 = 0; s4 < 64; s4 += 4) {
        #pragma unroll
        for (int p = 0; p < 4; ++p) {
            const int s = s4 + p;          // p compile-time, s4 uniform
            const int cur = p & 1;

            // ---- stage s+1 (issue early; completes under MFMA) ----
            if (s < 63) {
                // A: DMA into buf cur^1 (literal phase offsets off bumped ptr)
                #pragma unroll
                for (int i = 0; i < 5; ++i)
                    gld_lds16(aStage + p * 10240 + i * 2048,
                              aDstT + (cur ^ 1) * 10240 + i * 2048);
                // B: global -> regs for s+1 (uniform offset, SALU)
                const int sn = s + 1;
                const int ab = sn >> 2;
                const int uoff = ((ab >> 2) * 148 + (ab & 3)) * 256 + (sn & 3) * 32;
                const ushort* src = bT + uoff;
                Wh0 = *(const uint4*)src;
                Wh1 = *(const uint4*)(src + 8);
                Wl0 = *(const uint4*)(src + 128);
                Wl1 = *(const uint4*)(src + 136);
            }

            // ---- frag reads from buf cur (base VGPR + literal offsets) ----
            f16x8 fah[4], fal[4];
            #pragma unroll
            for (int mi = 0; mi < 4; ++mi) {
                fah[mi] = *(const f16x8*)(aBase + cur * 10240 + mi * 640);
                fal[mi] = *(const f16x8*)(aBase + cur * 10240 + 5120 + mi * 640);
            }
            #pragma unroll
            for (int ni = 0; ni < 4; ++ni) {
                f16x8 fbh = *(const f16x8*)(bBase + cur * 10240 + ni * 640);
                f16x8 fbl = *(const f16x8*)(bBase + cur * 10240 + 5120 + ni * 640);
                #pragma unroll
                for (int mi = 0; mi < 4; ++mi) {
                    accH[mi][ni] = __builtin_amdgcn_mfma_f32_16x16x32_f16(fah[mi], fbh, accH[mi][ni], 0, 0, 0);
                    accX[mi][ni] = __builtin_amdgcn_mfma_f32_16x16x32_f16(fah[mi], fbl, accX[mi][ni], 0, 0, 0);
                    accX[mi][ni] = __builtin_amdgcn_mfma_f32_16x16x32_f16(fal[mi], fbh, accX[mi][ni], 0, 0, 0);
                }
            }

            // ---- write B(s+1) into buf cur^1 (zero VALU) ----
            if (s < 63) {
                ushort* dh = bW + (cur ^ 1) * 10240;
                *(uint4*)dh = Wh0;
                *(uint4*)(dh + 8) = Wh1;
                *(uint4*)(dh + 5120) = Wl0;
                *(uint4*)(dh + 5128) = Wl1;
            }
            __syncthreads();               // one barrier per step
        }
        aStage += 40960;                   // 4 steps' worth of A source
    }

    // ---- epilogue: combine, normalize, activate, store ----
    #pragma unroll
    for (int mi = 0; mi < 4; ++mi) {
        #pragma unroll
        for (int ni = 0; ni < 4; ++ni) {
            int y = ny0 + wn_ * 4 + ni;
            int x = nx0 + lm;
            if (y < HO && x < HO) {
                float wv = wnorm[y * HO + x];
                f32x4 vh = accH[mi][ni];
                f32x4 vx = accX[mi][ni];
                #pragma unroll
                for (int r = 0; r < 4; ++r) {
                    int p = p0 + wm * 64 + mi * 16 + lg * 4 + r;
                    float num = vh[r] + vx[r] * (1.0f / 2048.0f);
                    float c = num / (pn[p] * wv + EPSF);
                    out[(long)p * (HO * HO) + y * HO + x] = activate(c);
                }
            }
        }
    }
}

// ---------------- pyramid device bodies ----------------
__device__ __forceinline__ void maxpool_body(const float* __restrict__ in,
                                             float* __restrict__ out,
                                             int idx, int h, int hp) {
    int s = idx % hp;
    int r = (idx / hp) % hp;
    int g = idx / (hp * hp);
    const float* base = in + (long)g * h * h;
    int y0 = 2 * r - 1, x0 = 2 * s - 1;
    float m = -1e30f;
    #pragma unroll
    for (int dy = 0; dy < 3; ++dy) {
        int y = y0 + dy;
        if ((unsigned)y >= (unsigned)h) continue;
        #pragma unroll
        for (int dx = 0; dx < 3; ++dx) {
            int x = x0 + dx;
            if ((unsigned)x >= (unsigned)h) continue;
            m = fmaxf(m, base[y * h + x]);
        }
    }
    out[idx] = m;
}

__device__ __forceinline__ void sparse_body(const float* __restrict__ pooled,
                                            float* __restrict__ out,
                                            int idx, int G2, int h) {
    int x = idx % h;
    int y = (idx / h) % h;
    int J = (idx / (h * h)) % G2;
    int I = idx / (h * h * G2);
    int G = 2 * G2;
    float s = 0.f;
    #pragma unroll
    for (int di = 0; di < 2; ++di) {
        int yy = y + 1 - 2 * di;
        if ((unsigned)yy >= (unsigned)h) continue;
        #pragma unroll
        for (int dj = 0; dj < 2; ++dj) {
            int xx = x + 1 - 2 * dj;
            if ((unsigned)xx >= (unsigned)h) continue;
            s += pooled[((((2 * I + di) * G) + (2 * J + dj)) * (long)h + yy) * h + xx];
        }
    }
    out[idx] = activate(0.25f * s);
}

__device__ __forceinline__ void unpool_body(float* __restrict__ lo,
                                            const float* __restrict__ pooled,
                                            const float* __restrict__ up,
                                            int idx, int G, int hl, int hp) {
    int x = idx % hl;
    int y = (idx / hl) % hl;
    int gj = (idx / (hl * hl)) % G;
    int gi = idx / (hl * hl * G);
    float l = lo[idx];
    float m = pooled[(((long)gi * G + gj) * hp + (y >> 1)) * hp + (x >> 1)];
    if (l == m) {
        int ry = (y >> 1) - 1 + 2 * (gi & 1);
        int rx = (x >> 1) - 1 + 2 * (gj & 1);
        float uv = 0.f;
        if ((unsigned)ry < (unsigned)hp && (unsigned)rx < (unsigned)hp)
            uv = up[((((long)(gi >> 1)) * (G >> 1) + (gj >> 1)) * hp + ry) * hp + rx];
        lo[idx] = fmaxf(l, uv);
    }
}

// ---------------- standalone pyramid kernels (big levels) ----------------
__global__ void maxpool_k(const float* __restrict__ in, float* __restrict__ out,
                          int GG, int h, int hp) {
    int idx = blockIdx.x * 256 + threadIdx.x;
    if (idx >= GG * hp * hp) return;
    maxpool_body(in, out, idx, h, hp);
}

__global__ void sparse_fwd_k(const float* __restrict__ pooled, float* __restrict__ out,
                             int G2, int h) {
    int idx = blockIdx.x * 256 + threadIdx.x;
    if (idx >= G2 * G2 * h * h) return;
    sparse_body(pooled, out, idx, G2, h);
}

__global__ void unpool_k(float* __restrict__ lo, const float* __restrict__ pooled,
                         const float* __restrict__ up, int G, int hl, int hp) {
    int idx = blockIdx.x * 256 + threadIdx.x;
    if (idx >= G * G * hl * hl) return;
    unpool_body(lo, pooled, up, idx, G, hl, hp);
}

// ---------------- fused small levels (3..5 fwd + unpool 5->4->3->2), 1 block ----------------
__global__ void small_levels(float* __restrict__ pyr2,
                             float* __restrict__ pool3, float* __restrict__ pyr3,
                             float* __restrict__ pool4, float* __restrict__ pyr4,
                             float* __restrict__ pool5, float* __restrict__ pyr5)
{
    const int t = threadIdx.x;
    for (int i = t; i < 64 * 17 * 17; i += 1024) maxpool_body(pyr2, pool3, i, 33, 17);
    __syncthreads();
    for (int i = t; i < 16 * 17 * 17; i += 1024) sparse_body(pool3, pyr3, i, 4, 17);
    __syncthreads();
    for (int i = t; i < 16 * 9 * 9; i += 1024) maxpool_body(pyr3, pool4, i, 17, 9);
    __syncthreads();
    for (int i = t; i < 4 * 9 * 9; i += 1024) sparse_body(pool4, pyr4, i, 2, 9);
    __syncthreads();
    for (int i = t; i < 4 * 5 * 5; i += 1024) maxpool_body(pyr4, pool5, i, 9, 5);
    __syncthreads();
    for (int i = t; i < 5 * 5; i += 1024) sparse_body(pool5, pyr5, i, 1, 5);
    __syncthreads();
    for (int i = t; i < 4 * 9 * 9; i += 1024) unpool_body(pyr4, pool5, pyr5, i, 2, 9, 5);
    __syncthreads();
    for (int i = t; i < 16 * 17 * 17; i += 1024) unpool_body(pyr3, pool4, pyr4, i, 4, 17, 9);
    __syncthreads();
    for (int i = t; i < 64 * 33 * 33; i += 1024) unpool_body(pyr2, pool3, pyr3, i, 8, 33, 17);
}

// ---------------- workspace layout (floats) ----------------
// d2p: 140*148*2*128 = 5,304,320 ushorts = 2,652,160 floats
// Ag:  8*64*2*128*40 = 5,242,880 ushorts = 2,621,440 floats
#define PN_OFF    0L
#define WN_OFF    1024L
#define SQ_OFF    17728L
#define CBASE     34112L
#define D2P_OFF   (CBASE)                  // [CBASE, CBASE+2,652,160)
#define AG_OFF    (CBASE + 2652160L)       // [.., CBASE+5,273,600)
// pyramid phase (aliases conv-phase buffers; disjoint in time):
#define POOL1_OFF (CBASE)                  // 4,326,400
#define PYR1_OFF  (CBASE + 4326400L)       // 1,081,600
#define POOL2_OFF (CBASE + 5408000L)       // 278,784
#define PYR2_OFF  (CBASE + 5686784L)       // 69,696
#define POOL3_OFF (CBASE + 5756480L)       // 18,496
#define PYR3_OFF  (CBASE + 5774976L)       // 4,624
#define POOL4_OFF (CBASE + 5779600L)       // 1,296
#define PYR4_OFF  (CBASE + 5780896L)       // 324
#define POOL5_OFF (CBASE + 5781220L)       // 100
#define PYR5_OFF  (CBASE + 5781320L)       // 25

extern "C" void kernel_launch(void* const* d_in, const int* in_sizes, int n_in,
                              void* d_out, int out_size, void* d_ws, size_t ws_size,
                              hipStream_t stream) {
    const float* d1 = (const float*)d_in[0];
    const float* d2 = (const float*)d_in[1];
    float* out = (float*)d_out;
    float* ws = (float*)d_ws;

    float* pnf   = ws + PN_OFF;
    float* wnf   = ws + WN_OFF;
    float* sqf   = ws + SQ_OFF;
    ushort* d2p  = (ushort*)(ws + D2P_OFF);
    ushort* Ag   = (ushort*)(ws + AG_OFF);
    float* pool1 = ws + POOL1_OFF;
    float* pyr1  = ws + PYR1_OFF;
    float* pool2 = ws + POOL2_OFF;
    float* pyr2  = ws + PYR2_OFF;
    float* pool3 = ws + POOL3_OFF;
    float* pyr3  = ws + PYR3_OFF;
    float* pool4 = ws + POOL4_OFF;
    float* pyr4  = ws + PYR4_OFF;
    float* pool5 = ws + POOL5_OFF;
    float* pyr5  = ws + PYR5_OFF;

    // prep
    prep_d2<<<(140 * 148 * 128 + 255) / 256, 256, 0, stream>>>(d2, d2p);
    build_Afrag<<<(8 * 64 * 2 * 128 * 40 + 255) / 256, 256, 0, stream>>>(d1, Ag);
    pnorm_k<<<1024, 64, 0, stream>>>(d1, pnf);
    sq_k<<<64, 256, 0, stream>>>(d2, sqf);
    wnorm_k<<<(HO * HO + 255) / 256, 256, 0, stream>>>(sqf, wnf);

    // correlation GEMM (MFMA) + normalize + activation -> pyramid0 in d_out
    conv_mfma<<<8 * 153, 256, 0, stream>>>(Ag, d2p, pnf, wnf, out);

    // forward pyramid, levels 0->2 (big)
    maxpool_k<<<(1024 * 65 * 65 + 255) / 256, 256, 0, stream>>>(out, pool1, 1024, 129, 65);
    sparse_fwd_k<<<(256 * 65 * 65 + 255) / 256, 256, 0, stream>>>(pool1, pyr1, 16, 65);
    maxpool_k<<<(256 * 33 * 33 + 255) / 256, 256, 0, stream>>>(pyr1, pool2, 256, 65, 33);
    sparse_fwd_k<<<(64 * 33 * 33 + 255) / 256, 256, 0, stream>>>(pool2, pyr2, 8, 33);

    // fused small levels: mp3..sf5 + unpool 5->4->3->2 (updates pyr2 in place)
    small_levels<<<1, 1024, 0, stream>>>(pyr2, pool3, pyr3, pool4, pyr4, pool5, pyr5);

    // remaining unpool chain
    unpool_k<<<(256 * 4225 + 255) / 256, 256, 0, stream>>>(pyr1, pool2, pyr2, 16, 65, 33);
    unpool_k<<<(1024 * 16641 + 255) / 256, 256, 0, stream>>>(out, pool1, pyr1, 32, 129, 65);
}